// Round 13
// baseline (258.347 us; speedup 1.0000x reference)
//
#include <hip/hip_runtime.h>
#include <hip/hip_fp16.h>
#include <math.h>

// ---------------------------------------------------------------------------
// PointTransformerNet forward, 6 kernels + memset:
//   memset(count8) ; hist+proj1 ; scan ; scatter ; E1+proj2 ; E2+head
//
// R13: 8-way partial histograms keyed by blockIdx&7 (XCD swizzle class).
// R12 showed hist_proj1 at 46us, VALUBusy 7%, ~7 atomics/cycle device-wide,
// WRITE_SIZE 2.5x the real bytes -- the classic cross-XCD atomic line-thrash.
// count8[j][d] is only updated by swizzle class j -> 8x less same-line
// contention, no cross-XCD migration. Scatter uses the IDENTICAL grid-stride
// mapping as hist so edge->j is consistent; final slot =
// offsets[d] + sum_{j'<j} cnt_{j'}[d] + rank  (computed as base8[j][d]+rank).
//
// Payload: bf16x2 (E hi16, E*vv lo16), E = e^{-(a_src+c)} per src node.
// Factored softmax (per-dst exp cancels): h = relu(dv + sum(Ev)/sum(E)).
// Per edge: one 4B gather + and/shl unpack + two v_add_f32.
// R12 A/B: launch_bounds(256,8) occupancy > per-node instr count (R11).
// R5: grid.sync on gfx950 ~200us each -- never.
// ---------------------------------------------------------------------------

#define LOG2E 1.44269504088896340736f

typedef _Float16 hf2 __attribute__((ext_vector_type(2)));
union H2U { __half2 hh; hf2 hf; unsigned u; };

#if defined(__has_builtin)
#if __has_builtin(__builtin_amdgcn_fdot2)
#define HAVE_FDOT2 1
#endif
#endif

__device__ __forceinline__ float fdot2(hf2 a, hf2 b, float c) {
#ifdef HAVE_FDOT2
    return __builtin_amdgcn_fdot2(a, b, c, false);
#else
    return fmaf((float)a.x, (float)b.x, fmaf((float)a.y, (float)b.y, c));
#endif
}

__device__ __forceinline__ unsigned bf16_rn(float x) {
    unsigned b = __float_as_uint(x);
    return (b + 0x7FFFu + ((b >> 16) & 1u)) >> 16;   // round-to-nearest-even
}

// Payload: (E hi16, E*vv lo16) as bf16. Clamp at +-86 is an f32-inf guard
// only (|a+c| <= ~15 in practice).
__device__ __forceinline__ unsigned pack_payload(float a_plus_c, float vv) {
    float t = fminf(fmaxf(-a_plus_c * LOG2E, -86.0f), 86.0f);
    float E = exp2f(t);
    return (bf16_rn(E) << 16) | bf16_rn(E * vv);
}

// hist into 8-way partial counters (1 atomic/edge, rank within partial) +
// conv1 payload, grid-strided. MUST keep gridDim=2048, blockDim=256 so the
// e->blockIdx mapping matches scatter_kernel exactly.
__global__ void __launch_bounds__(256) hist_proj1_kernel(
        const int* __restrict__ dst, int* __restrict__ count8, int* __restrict__ rank,
        const float* __restrict__ x, const float* __restrict__ pos,
        const float* __restrict__ W1_src, const float* __restrict__ W1_val,
        const float* __restrict__ W1_pos,
        unsigned* __restrict__ g1, int N, int E) {
    int gtid = blockIdx.x * 256 + threadIdx.x;
    int gsz = gridDim.x * 256;
    int* cnt = count8 + (blockIdx.x & 7) * N;   // this swizzle class's partial
    for (int e = gtid; e < E; e += gsz)
        rank[e] = atomicAdd(&cnt[dst[e]], 1);

    int lane = threadIdx.x & 63, wid = threadIdx.x >> 6;
    float ws0 = W1_src[lane], ws1 = W1_src[64 + lane], ws2 = W1_src[128 + lane];
    float wv0 = W1_val[lane], wv1 = W1_val[64 + lane], wv2 = W1_val[128 + lane];
    float wp0 = W1_pos[lane], wp1 = W1_pos[64 + lane], wp2 = W1_pos[128 + lane];
    int nwav = gridDim.x * 4;
    for (int node = blockIdx.x * 4 + wid; node < N; node += nwav) {
        float x0 = x[node * 3 + 0], x1 = x[node * 3 + 1], x2 = x[node * 3 + 2];
        float p0 = pos[node * 3 + 0], p1 = pos[node * 3 + 1], p2 = pos[node * 3 + 2];
        float as = fmaf(x0, ws0, fmaf(x1, ws1, x2 * ws2));
        float vv = fmaf(x0, wv0, fmaf(x1, wv1, x2 * wv2));
        float cc = fmaf(p0, wp0, fmaf(p1, wp1, p2 * wp2));
        g1[node * 64 + lane] = pack_payload(as + cc, vv - cc);
    }
}

// Scan over 8 partial histograms: emits global CSR offsets AND per-partial
// bases base8[j][d] = offsets[d] + sum_{j'<j} cnt_{j'}[d].
// Block b redundantly reduces totals of nodes [0, b*1024) for its base.
__global__ void __launch_bounds__(256) scan_kernel(
        const int* __restrict__ count8, int* __restrict__ offsets,
        int* __restrict__ base8, int n, int nsb) {
    __shared__ int red[4];
    __shared__ int wpre[4];
    int tid = threadIdx.x, lane = tid & 63, wid = tid >> 6;
    int lim = blockIdx.x * 1024;
    int s = 0;
    #pragma unroll
    for (int j = 0; j < 8; ++j) {
        const int* cj = count8 + j * n;
        for (int i = tid * 4; i < lim; i += 1024) {
            int4 c = *(const int4*)&cj[i];
            s += c.x + c.y + c.z + c.w;
        }
    }
    #pragma unroll
    for (int off = 32; off >= 1; off >>= 1) s += __shfl_down(s, off);
    if (lane == 0) red[wid] = s;
    __syncthreads();
    int base = red[0] + red[1] + red[2] + red[3];

    // local chunk: 4 nodes/thread, 8 partials each
    int b4 = lim + tid * 4;
    int c[8][4];
    #pragma unroll
    for (int j = 0; j < 8; ++j) {
        int4 v = make_int4(0, 0, 0, 0);
        if (b4 + 3 < n) {
            v = *(const int4*)&count8[j * n + b4];
        } else {
            if (b4 + 0 < n) v.x = count8[j * n + b4 + 0];
            if (b4 + 1 < n) v.y = count8[j * n + b4 + 1];
            if (b4 + 2 < n) v.z = count8[j * n + b4 + 2];
        }
        c[j][0] = v.x; c[j][1] = v.y; c[j][2] = v.z; c[j][3] = v.w;
    }
    int tot[4];
    #pragma unroll
    for (int k = 0; k < 4; ++k) {
        tot[k] = 0;
        #pragma unroll
        for (int j = 0; j < 8; ++j) tot[k] += c[j][k];
    }
    int tsum = tot[0] + tot[1] + tot[2] + tot[3];
    int inc = tsum;
    #pragma unroll
    for (int off = 1; off < 64; off <<= 1) {
        int t2 = __shfl_up(inc, off);
        if (lane >= off) inc += t2;
    }
    if (lane == 63) wpre[wid] = inc;
    __syncthreads();
    int wbase = 0;
    for (int q = 0; q < wid; ++q) wbase += wpre[q];
    int run = base + wbase + (inc - tsum);   // exclusive offset of node b4
    #pragma unroll
    for (int k = 0; k < 4; ++k) {
        int i = b4 + k;
        if (i < n) {
            offsets[i] = run;
            int pb = run;
            #pragma unroll
            for (int j = 0; j < 8; ++j) {
                base8[j * n + i] = pb;
                pb += c[j][k];
            }
            run += tot[k];
        }
    }
    if ((int)blockIdx.x == nsb - 1 && tid == 0)
        offsets[n] = base + wpre[0] + wpre[1] + wpre[2] + wpre[3];
}

// Atomic-free scatter: slot = base8[blockSwizzle][dst] + rank.
// Grid MUST be 2048x256 grid-stride (same e->blockIdx map as hist).
__global__ void __launch_bounds__(256) scatter_kernel(
        const int* __restrict__ src, const int* __restrict__ dst,
        const int* __restrict__ rank, const int* __restrict__ base8,
        int* __restrict__ sorted_src, int N, int E) {
    int gtid = blockIdx.x * 256 + threadIdx.x;
    int gsz = gridDim.x * 256;
    const int* bj = base8 + (blockIdx.x & 7) * N;
    for (int e = gtid; e < E; e += gsz)
        sorted_src[bj[dst[e]] + rank[e]] = src[e];
}

// Per-edge accumulate: unpack bf16x2 payload (and/shl) + two adds.
__device__ __forceinline__ void eacc(unsigned u, float& s, float& n) {
    s += __uint_as_float(u & 0xFFFF0000u);
    n += __uint_as_float(u << 16);
}

// Segment aggregate: returns relu(dv + sum(Ev)/sum(E)).
// Per edge: one 4B gather + 4 VALU. 8-deep pipelined, scalar addressing.
__device__ __forceinline__ float edge_node(
        int node, int laneoff,
        const int* __restrict__ offsets, const int* __restrict__ ss,
        const char* __restrict__ gbase, float dv) {
    int beg = offsets[node], end = offsets[node + 1];
    if (beg >= end) return 0.f;           // degree-0: reference gives 0
    float s0 = 0.f, n0 = 0.f, s1 = 0.f, n1 = 0.f;
    int e = beg;
    int aligned = min((beg + 3) & ~3, end);    // peel to 16B alignment of ss
    for (; e < aligned; ++e) {
        int i0 = __builtin_amdgcn_readfirstlane(ss[e]);
        unsigned g0 = *(const unsigned*)(gbase + (((size_t)(unsigned)i0) << 8) + laneoff);
        eacc(g0, s0, n0);
    }
    for (; e + 8 <= end; e += 8) {
        int4 ia = *(const int4*)(ss + e);
        int4 ib = *(const int4*)(ss + e + 4);
        int i0 = __builtin_amdgcn_readfirstlane(ia.x);
        int i1 = __builtin_amdgcn_readfirstlane(ia.y);
        int i2 = __builtin_amdgcn_readfirstlane(ia.z);
        int i3 = __builtin_amdgcn_readfirstlane(ia.w);
        int i4 = __builtin_amdgcn_readfirstlane(ib.x);
        int i5 = __builtin_amdgcn_readfirstlane(ib.y);
        int i6 = __builtin_amdgcn_readfirstlane(ib.z);
        int i7 = __builtin_amdgcn_readfirstlane(ib.w);
        unsigned g0 = *(const unsigned*)(gbase + (((size_t)(unsigned)i0) << 8) + laneoff);
        unsigned g1 = *(const unsigned*)(gbase + (((size_t)(unsigned)i1) << 8) + laneoff);
        unsigned g2 = *(const unsigned*)(gbase + (((size_t)(unsigned)i2) << 8) + laneoff);
        unsigned g3 = *(const unsigned*)(gbase + (((size_t)(unsigned)i3) << 8) + laneoff);
        unsigned g4 = *(const unsigned*)(gbase + (((size_t)(unsigned)i4) << 8) + laneoff);
        unsigned g5 = *(const unsigned*)(gbase + (((size_t)(unsigned)i5) << 8) + laneoff);
        unsigned g6 = *(const unsigned*)(gbase + (((size_t)(unsigned)i6) << 8) + laneoff);
        unsigned g7 = *(const unsigned*)(gbase + (((size_t)(unsigned)i7) << 8) + laneoff);
        eacc(g0, s0, n0);
        eacc(g1, s1, n1);
        eacc(g2, s0, n0);
        eacc(g3, s1, n1);
        eacc(g4, s0, n0);
        eacc(g5, s1, n1);
        eacc(g6, s0, n0);
        eacc(g7, s1, n1);
    }
    for (; e + 4 <= end; e += 4) {
        int4 ia = *(const int4*)(ss + e);
        int i0 = __builtin_amdgcn_readfirstlane(ia.x);
        int i1 = __builtin_amdgcn_readfirstlane(ia.y);
        int i2 = __builtin_amdgcn_readfirstlane(ia.z);
        int i3 = __builtin_amdgcn_readfirstlane(ia.w);
        unsigned g0 = *(const unsigned*)(gbase + (((size_t)(unsigned)i0) << 8) + laneoff);
        unsigned g1 = *(const unsigned*)(gbase + (((size_t)(unsigned)i1) << 8) + laneoff);
        unsigned g2 = *(const unsigned*)(gbase + (((size_t)(unsigned)i2) << 8) + laneoff);
        unsigned g3 = *(const unsigned*)(gbase + (((size_t)(unsigned)i3) << 8) + laneoff);
        eacc(g0, s0, n0);
        eacc(g1, s1, n1);
        eacc(g2, s0, n0);
        eacc(g3, s1, n1);
    }
    for (; e < end; ++e) {
        int i0 = __builtin_amdgcn_readfirstlane(ss[e]);
        unsigned g0 = *(const unsigned*)(gbase + (((size_t)(unsigned)i0) << 8) + laneoff);
        eacc(g0, s0, n0);
    }
    float s = s0 + s1;
    float r = __builtin_amdgcn_rcpf(s + 1e-37f);
    return fmaxf(fmaf(n0 + n1, r, dv), 0.f);
}

// E1 + proj2 fused, grid-strided, launch_bounds(256,8).
// proj2 dot: W2 staged in LDS as b128 k-quads; per node: 16 ds_read_b128 +
// 16 b64 h-broadcasts + 64 fdot2.
__global__ void __launch_bounds__(256, 8) e1p2_kernel(
        const float* __restrict__ pos,
        const int* __restrict__ offsets, const int* __restrict__ sorted_src,
        const unsigned* __restrict__ g1,
        const float* __restrict__ W1_pos, const float* __restrict__ b1_pos,
        const float* __restrict__ W2_src, const float* __restrict__ W2_val,
        const float* __restrict__ W2_pos,
        unsigned* __restrict__ g2, int N) {
    __shared__ uint4 W4q[16 * 64];    // [q][c]: k-quad (s01,s23,v01,v23), 16KB
    __shared__ __half hsh[4][64];
    int tid = threadIdx.x, lane = tid & 63, wid = tid >> 6;
    for (int idx = tid; idx < 1024; idx += 256) {
        int q = idx >> 6, c = idx & 63, k = 4 * q;
        H2U s01, s23, v01, v23;
        s01.hh = __floats2half2_rn(W2_src[k * 64 + c], W2_src[(k + 1) * 64 + c]);
        s23.hh = __floats2half2_rn(W2_src[(k + 2) * 64 + c], W2_src[(k + 3) * 64 + c]);
        v01.hh = __floats2half2_rn(W2_val[k * 64 + c], W2_val[(k + 1) * 64 + c]);
        v23.hh = __floats2half2_rn(W2_val[(k + 2) * 64 + c], W2_val[(k + 3) * 64 + c]);
        W4q[idx] = make_uint4(s01.u, s23.u, v01.u, v23.u);
    }
    __syncthreads();

    float w1p0 = W1_pos[lane], w1p1 = W1_pos[64 + lane], w1p2 = W1_pos[128 + lane];
    float bp1 = b1_pos[lane];
    float w2p0 = W2_pos[lane], w2p1 = W2_pos[64 + lane], w2p2 = W2_pos[128 + lane];
    int laneoff = lane * 4;
    int nwav = gridDim.x * 4;

    for (int node = blockIdx.x * 4 + wid; node < N; node += nwav) {
        float p0 = pos[node * 3 + 0], p1 = pos[node * 3 + 1], p2 = pos[node * 3 + 2];
        float dpos = fmaf(p0, w1p0, fmaf(p1, w1p1, p2 * w1p2));
        float hval = edge_node(node, laneoff, offsets, sorted_src,
                               (const char*)g1, dpos + bp1);
        hsh[wid][lane] = __float2half(hval);   // same-wave publish (all lanes)
        const uint2* hq = (const uint2*)hsh[wid];
        float as = 0.f, vv = 0.f;
        #pragma unroll 4
        for (int q = 0; q < 16; ++q) {
            uint2 hu = hq[q];                  // b64 broadcast: h quad
            H2U h01, h23; h01.u = hu.x; h23.u = hu.y;
            uint4 wq = W4q[q * 64 + lane];     // ds_read_b128
            H2U a0, a1, b0, b1;
            a0.u = wq.x; a1.u = wq.y; b0.u = wq.z; b1.u = wq.w;
            as = fdot2(h01.hf, a0.hf, as);
            as = fdot2(h23.hf, a1.hf, as);
            vv = fdot2(h01.hf, b0.hf, vv);
            vv = fdot2(h23.hf, b1.hf, vv);
        }
        float cc = fmaf(p0, w2p0, fmaf(p1, w2p1, p2 * w2p2));
        g2[node * 64 + lane] = pack_payload(as + cc, vv - cc);
    }
}

// E2 + fused relu/fc1/relu/fc2 head, grid-strided. fc1 via fdot2 with Wfc1
// pairs held in 16 VGPRs (fits the 64-VGPR budget at 8 waves/EU).
__global__ void __launch_bounds__(256, 8) e2head_kernel(
        const float* __restrict__ pos,
        const int* __restrict__ offsets, const int* __restrict__ sorted_src,
        const unsigned* __restrict__ g2,
        const float* __restrict__ W2_pos, const float* __restrict__ b2_pos,
        const float* __restrict__ Wfc1, const float* __restrict__ bfc1,
        const float* __restrict__ Wfc2, const float* __restrict__ bfc2,
        float* __restrict__ out, int N) {
    __shared__ __half hsh[4][64];
    int tid = threadIdx.x, lane = tid & 63, wid = tid >> 6;
    int c = lane & 31, khb = (lane >> 5) * 16;
    unsigned Wr[16];                  // this lane's fc1 k-pairs (16 VGPRs)
    #pragma unroll
    for (int j = 0; j < 16; ++j) {
        H2U w;
        w.hh = __floats2half2_rn(Wfc1[(2 * (khb + j)) * 32 + c],
                                 Wfc1[(2 * (khb + j) + 1) * 32 + c]);
        Wr[j] = w.u;
    }

    float wp0 = W2_pos[lane], wp1 = W2_pos[64 + lane], wp2 = W2_pos[128 + lane];
    float bp = b2_pos[lane];
    float bfc1c = bfc1[c], wfc2c = Wfc2[c], bias2 = bfc2[0];
    int laneoff = lane * 4;
    int nwav = gridDim.x * 4;

    for (int node = blockIdx.x * 4 + wid; node < N; node += nwav) {
        float p0 = pos[node * 3 + 0], p1 = pos[node * 3 + 1], p2 = pos[node * 3 + 2];
        float dpos = fmaf(p0, wp0, fmaf(p1, wp1, p2 * wp2));
        float hval = edge_node(node, laneoff, offsets, sorted_src,
                               (const char*)g2, dpos + bp);
        hsh[wid][lane] = __float2half(hval);   // all-lane same-wave publish
        const hf2* h2 = (const hf2*)hsh[wid];
        float t2 = 0.f;
        #pragma unroll
        for (int j = 0; j < 16; ++j) {
            hf2 hk = h2[khb + j];              // 4B broadcast read
            H2U w; w.u = Wr[j];
            t2 = fdot2(hk, w.hf, t2);
        }
        t2 += __shfl_down(t2, 32);             // all lanes execute
        t2 = fmaxf(t2 + bfc1c, 0.f) * wfc2c;
        t2 = (lane < 32) ? t2 : 0.f;
        #pragma unroll
        for (int off = 16; off >= 1; off >>= 1) t2 += __shfl_down(t2, off);
        if (lane == 0) out[node] = t2 + bias2;
    }
}

extern "C" void kernel_launch(void* const* d_in, const int* in_sizes, int n_in,
                              void* d_out, int out_size, void* d_ws, size_t ws_size,
                              hipStream_t stream) {
    const float* x   = (const float*)d_in[0];
    const float* pos = (const float*)d_in[1];
    const int* eidx  = (const int*)d_in[2];
    const float* W1_src = (const float*)d_in[4];
    // d_in[5] = W1_dst: cancels in softmax
    const float* W1_val = (const float*)d_in[6];
    const float* W1_pos = (const float*)d_in[7];
    const float* b1_pos = (const float*)d_in[8];
    const float* W2_src = (const float*)d_in[9];
    // d_in[10] = W2_dst: cancels in softmax
    const float* W2_val = (const float*)d_in[11];
    const float* W2_pos = (const float*)d_in[12];
    const float* b2_pos = (const float*)d_in[13];
    const float* W_fc1  = (const float*)d_in[14];
    const float* b_fc1  = (const float*)d_in[15];
    const float* W_fc2  = (const float*)d_in[16];
    const float* b_fc2  = (const float*)d_in[17];

    const int N = in_sizes[0] / 3;
    const int E = in_sizes[2] / 2;
    const int* src = eidx;
    const int* dst = eidx + E;
    const int nsb = (N + 1023) / 1024;   // 49 for N=50K

    char* w = (char*)d_ws;
    auto carve = [&](size_t bytes) -> void* {
        void* p = (void*)w;
        w += (bytes + 255) & ~size_t(255);
        return p;
    };
    int*      count8     = (int*)carve((size_t)8 * N * 4);
    int*      offsets    = (int*)carve((size_t)(N + 1) * 4);
    int*      base8      = (int*)carve((size_t)8 * N * 4);
    int*      rank       = (int*)carve((size_t)E * 4);
    int*      sorted_src = (int*)carve((size_t)E * 4);
    unsigned* g1         = (unsigned*)carve((size_t)N * 64 * 4);
    unsigned* g2         = (unsigned*)carve((size_t)N * 64 * 4);

    hipMemsetAsync(count8, 0, (size_t)8 * N * 4, stream);
    hist_proj1_kernel<<<2048, 256, 0, stream>>>(
        dst, count8, rank, x, pos, W1_src, W1_val, W1_pos, g1, N, E);
    scan_kernel<<<nsb, 256, 0, stream>>>(count8, offsets, base8, N, nsb);
    scatter_kernel<<<2048, 256, 0, stream>>>(src, dst, rank, base8,
                                             sorted_src, N, E);
    e1p2_kernel<<<2048, 256, 0, stream>>>(
        pos, offsets, sorted_src, g1, W1_pos, b1_pos, W2_src, W2_val, W2_pos, g2, N);
    e2head_kernel<<<2048, 256, 0, stream>>>(
        pos, offsets, sorted_src, g2, W2_pos, b2_pos,
        W_fc1, b_fc1, W_fc2, b_fc2, (float*)d_out, N);
}

// Round 14
// 225.850 us; speedup vs baseline: 1.1439x; 1.1439x over previous
//
#include <hip/hip_runtime.h>
#include <hip/hip_fp16.h>
#include <math.h>

// ---------------------------------------------------------------------------
// PointTransformerNet forward, 7 dispatches:
//   memset(count8) ; hist+proj1 ; scan_sum ; scan_emit ; scatter ;
//   E1+proj2 ; E2+head
//
// R13 lesson: 8-way partial hist (blockIdx&7 swizzle) cuts the atomic storm,
// but the single-kernel redundant-base scan over 8N data ballooned to 45us
// (78MB of L2 reads on 49 blocks). R14: two-phase scan (R6-proven): per-chunk
// sums (parallel, 32KB/block) then emit with a trivial <=64-entry wave scan.
//
// Payload: bf16x2 (E hi16, E*vv lo16), E = e^{-(a_src+c)} per src node.
// Factored softmax (per-dst exp cancels): h = relu(dv + sum(Ev)/sum(E)).
// Per edge: one 4B gather + and/shl unpack + two v_add_f32.
// R12 A/B: launch_bounds(256,8) occupancy > per-node instr count.
// R5: grid.sync on gfx950 ~200us each -- never.
// ---------------------------------------------------------------------------

#define LOG2E 1.44269504088896340736f

typedef _Float16 hf2 __attribute__((ext_vector_type(2)));
union H2U { __half2 hh; hf2 hf; unsigned u; };

#if defined(__has_builtin)
#if __has_builtin(__builtin_amdgcn_fdot2)
#define HAVE_FDOT2 1
#endif
#endif

__device__ __forceinline__ float fdot2(hf2 a, hf2 b, float c) {
#ifdef HAVE_FDOT2
    return __builtin_amdgcn_fdot2(a, b, c, false);
#else
    return fmaf((float)a.x, (float)b.x, fmaf((float)a.y, (float)b.y, c));
#endif
}

__device__ __forceinline__ unsigned bf16_rn(float x) {
    unsigned b = __float_as_uint(x);
    return (b + 0x7FFFu + ((b >> 16) & 1u)) >> 16;   // round-to-nearest-even
}

// Payload: (E hi16, E*vv lo16) as bf16. Clamp at +-86 is an f32-inf guard
// only (|a+c| <= ~15 in practice).
__device__ __forceinline__ unsigned pack_payload(float a_plus_c, float vv) {
    float t = fminf(fmaxf(-a_plus_c * LOG2E, -86.0f), 86.0f);
    float E = exp2f(t);
    return (bf16_rn(E) << 16) | bf16_rn(E * vv);
}

// hist into 8-way partial counters (1 atomic/edge, rank within partial) +
// conv1 payload, grid-strided. MUST keep gridDim=2048, blockDim=256 so the
// e->blockIdx mapping matches scatter_kernel exactly.
__global__ void __launch_bounds__(256) hist_proj1_kernel(
        const int* __restrict__ dst, int* __restrict__ count8, int* __restrict__ rank,
        const float* __restrict__ x, const float* __restrict__ pos,
        const float* __restrict__ W1_src, const float* __restrict__ W1_val,
        const float* __restrict__ W1_pos,
        unsigned* __restrict__ g1, int N, int E) {
    int gtid = blockIdx.x * 256 + threadIdx.x;
    int gsz = gridDim.x * 256;
    int* cnt = count8 + (blockIdx.x & 7) * N;   // this swizzle class's partial
    for (int e = gtid; e < E; e += gsz)
        rank[e] = atomicAdd(&cnt[dst[e]], 1);

    int lane = threadIdx.x & 63, wid = threadIdx.x >> 6;
    float ws0 = W1_src[lane], ws1 = W1_src[64 + lane], ws2 = W1_src[128 + lane];
    float wv0 = W1_val[lane], wv1 = W1_val[64 + lane], wv2 = W1_val[128 + lane];
    float wp0 = W1_pos[lane], wp1 = W1_pos[64 + lane], wp2 = W1_pos[128 + lane];
    int nwav = gridDim.x * 4;
    for (int node = blockIdx.x * 4 + wid; node < N; node += nwav) {
        float x0 = x[node * 3 + 0], x1 = x[node * 3 + 1], x2 = x[node * 3 + 2];
        float p0 = pos[node * 3 + 0], p1 = pos[node * 3 + 1], p2 = pos[node * 3 + 2];
        float as = fmaf(x0, ws0, fmaf(x1, ws1, x2 * ws2));
        float vv = fmaf(x0, wv0, fmaf(x1, wv1, x2 * wv2));
        float cc = fmaf(p0, wp0, fmaf(p1, wp1, p2 * wp2));
        g1[node * 64 + lane] = pack_payload(as + cc, vv - cc);
    }
}

// Phase A: per-chunk (1024 nodes) totals across all 8 partials.
__global__ void __launch_bounds__(256) scan_sum_kernel(
        const int* __restrict__ count8, int* __restrict__ chunksum, int n) {
    __shared__ int red[4];
    int tid = threadIdx.x, lane = tid & 63, wid = tid >> 6;
    int b4 = blockIdx.x * 1024 + tid * 4;
    int s = 0;
    #pragma unroll
    for (int j = 0; j < 8; ++j) {
        int4 v = make_int4(0, 0, 0, 0);
        if (b4 + 3 < n) {
            v = *(const int4*)&count8[j * n + b4];
        } else {
            if (b4 + 0 < n) v.x = count8[j * n + b4 + 0];
            if (b4 + 1 < n) v.y = count8[j * n + b4 + 1];
            if (b4 + 2 < n) v.z = count8[j * n + b4 + 2];
        }
        s += v.x + v.y + v.z + v.w;
    }
    #pragma unroll
    for (int off = 32; off >= 1; off >>= 1) s += __shfl_down(s, off);
    if (lane == 0) red[wid] = s;
    __syncthreads();
    if (tid == 0) chunksum[blockIdx.x] = red[0] + red[1] + red[2] + red[3];
}

// Phase B: every block wave-scans the <=64 chunk totals for its base, then
// emits global CSR offsets AND per-partial bases
// base8[j][d] = offsets[d] + sum_{j'<j} cnt_{j'}[d].
__global__ void __launch_bounds__(256) scan_emit_kernel(
        const int* __restrict__ count8, const int* __restrict__ chunksum,
        int* __restrict__ offsets, int* __restrict__ base8, int n, int nsb) {
    __shared__ int sbase[2];
    __shared__ int wpre[4];
    int tid = threadIdx.x, lane = tid & 63, wid = tid >> 6;
    if (tid < 64) {                       // wave 0: scan chunk totals
        int v = (lane < nsb) ? chunksum[lane] : 0;
        int inc = v;
        #pragma unroll
        for (int off = 1; off < 64; off <<= 1) {
            int t2 = __shfl_up(inc, off);
            if (lane >= off) inc += t2;
        }
        if (lane == (int)blockIdx.x) sbase[0] = inc - v;   // this block's base
        if (lane == nsb - 1) sbase[1] = inc;               // grand total (=E)
    }

    // local chunk: 4 nodes/thread, 8 partials each
    int b4 = blockIdx.x * 1024 + tid * 4;
    int c[8][4];
    #pragma unroll
    for (int j = 0; j < 8; ++j) {
        int4 v = make_int4(0, 0, 0, 0);
        if (b4 + 3 < n) {
            v = *(const int4*)&count8[j * n + b4];
        } else {
            if (b4 + 0 < n) v.x = count8[j * n + b4 + 0];
            if (b4 + 1 < n) v.y = count8[j * n + b4 + 1];
            if (b4 + 2 < n) v.z = count8[j * n + b4 + 2];
        }
        c[j][0] = v.x; c[j][1] = v.y; c[j][2] = v.z; c[j][3] = v.w;
    }
    int tot[4];
    #pragma unroll
    for (int k = 0; k < 4; ++k) {
        tot[k] = 0;
        #pragma unroll
        for (int j = 0; j < 8; ++j) tot[k] += c[j][k];
    }
    int tsum = tot[0] + tot[1] + tot[2] + tot[3];
    int inc = tsum;
    #pragma unroll
    for (int off = 1; off < 64; off <<= 1) {
        int t2 = __shfl_up(inc, off);
        if (lane >= off) inc += t2;
    }
    if (lane == 63) wpre[wid] = inc;
    __syncthreads();                      // covers sbase and wpre
    int wbase = 0;
    for (int q = 0; q < wid; ++q) wbase += wpre[q];
    int run = sbase[0] + wbase + (inc - tsum);   // exclusive offset of node b4
    #pragma unroll
    for (int k = 0; k < 4; ++k) {
        int i = b4 + k;
        if (i < n) {
            offsets[i] = run;
            int pb = run;
            #pragma unroll
            for (int j = 0; j < 8; ++j) {
                base8[j * n + i] = pb;
                pb += c[j][k];
            }
            run += tot[k];
        }
    }
    if (blockIdx.x == 0 && tid == 0) offsets[n] = sbase[1];
}

// Atomic-free scatter: slot = base8[blockSwizzle][dst] + rank.
// Grid MUST be 2048x256 grid-stride (same e->blockIdx map as hist).
__global__ void __launch_bounds__(256) scatter_kernel(
        const int* __restrict__ src, const int* __restrict__ dst,
        const int* __restrict__ rank, const int* __restrict__ base8,
        int* __restrict__ sorted_src, int N, int E) {
    int gtid = blockIdx.x * 256 + threadIdx.x;
    int gsz = gridDim.x * 256;
    const int* bj = base8 + (blockIdx.x & 7) * N;
    for (int e = gtid; e < E; e += gsz)
        sorted_src[bj[dst[e]] + rank[e]] = src[e];
}

// Per-edge accumulate: unpack bf16x2 payload (and/shl) + two adds.
__device__ __forceinline__ void eacc(unsigned u, float& s, float& n) {
    s += __uint_as_float(u & 0xFFFF0000u);
    n += __uint_as_float(u << 16);
}

// Segment aggregate: returns relu(dv + sum(Ev)/sum(E)).
// Per edge: one 4B gather + 4 VALU. 8-deep pipelined, scalar addressing.
__device__ __forceinline__ float edge_node(
        int node, int laneoff,
        const int* __restrict__ offsets, const int* __restrict__ ss,
        const char* __restrict__ gbase, float dv) {
    int beg = offsets[node], end = offsets[node + 1];
    if (beg >= end) return 0.f;           // degree-0: reference gives 0
    float s0 = 0.f, n0 = 0.f, s1 = 0.f, n1 = 0.f;
    int e = beg;
    int aligned = min((beg + 3) & ~3, end);    // peel to 16B alignment of ss
    for (; e < aligned; ++e) {
        int i0 = __builtin_amdgcn_readfirstlane(ss[e]);
        unsigned g0 = *(const unsigned*)(gbase + (((size_t)(unsigned)i0) << 8) + laneoff);
        eacc(g0, s0, n0);
    }
    for (; e + 8 <= end; e += 8) {
        int4 ia = *(const int4*)(ss + e);
        int4 ib = *(const int4*)(ss + e + 4);
        int i0 = __builtin_amdgcn_readfirstlane(ia.x);
        int i1 = __builtin_amdgcn_readfirstlane(ia.y);
        int i2 = __builtin_amdgcn_readfirstlane(ia.z);
        int i3 = __builtin_amdgcn_readfirstlane(ia.w);
        int i4 = __builtin_amdgcn_readfirstlane(ib.x);
        int i5 = __builtin_amdgcn_readfirstlane(ib.y);
        int i6 = __builtin_amdgcn_readfirstlane(ib.z);
        int i7 = __builtin_amdgcn_readfirstlane(ib.w);
        unsigned g0 = *(const unsigned*)(gbase + (((size_t)(unsigned)i0) << 8) + laneoff);
        unsigned g1 = *(const unsigned*)(gbase + (((size_t)(unsigned)i1) << 8) + laneoff);
        unsigned g2 = *(const unsigned*)(gbase + (((size_t)(unsigned)i2) << 8) + laneoff);
        unsigned g3 = *(const unsigned*)(gbase + (((size_t)(unsigned)i3) << 8) + laneoff);
        unsigned g4 = *(const unsigned*)(gbase + (((size_t)(unsigned)i4) << 8) + laneoff);
        unsigned g5 = *(const unsigned*)(gbase + (((size_t)(unsigned)i5) << 8) + laneoff);
        unsigned g6 = *(const unsigned*)(gbase + (((size_t)(unsigned)i6) << 8) + laneoff);
        unsigned g7 = *(const unsigned*)(gbase + (((size_t)(unsigned)i7) << 8) + laneoff);
        eacc(g0, s0, n0);
        eacc(g1, s1, n1);
        eacc(g2, s0, n0);
        eacc(g3, s1, n1);
        eacc(g4, s0, n0);
        eacc(g5, s1, n1);
        eacc(g6, s0, n0);
        eacc(g7, s1, n1);
    }
    for (; e + 4 <= end; e += 4) {
        int4 ia = *(const int4*)(ss + e);
        int i0 = __builtin_amdgcn_readfirstlane(ia.x);
        int i1 = __builtin_amdgcn_readfirstlane(ia.y);
        int i2 = __builtin_amdgcn_readfirstlane(ia.z);
        int i3 = __builtin_amdgcn_readfirstlane(ia.w);
        unsigned g0 = *(const unsigned*)(gbase + (((size_t)(unsigned)i0) << 8) + laneoff);
        unsigned g1 = *(const unsigned*)(gbase + (((size_t)(unsigned)i1) << 8) + laneoff);
        unsigned g2 = *(const unsigned*)(gbase + (((size_t)(unsigned)i2) << 8) + laneoff);
        unsigned g3 = *(const unsigned*)(gbase + (((size_t)(unsigned)i3) << 8) + laneoff);
        eacc(g0, s0, n0);
        eacc(g1, s1, n1);
        eacc(g2, s0, n0);
        eacc(g3, s1, n1);
    }
    for (; e < end; ++e) {
        int i0 = __builtin_amdgcn_readfirstlane(ss[e]);
        unsigned g0 = *(const unsigned*)(gbase + (((size_t)(unsigned)i0) << 8) + laneoff);
        eacc(g0, s0, n0);
    }
    float s = s0 + s1;
    float r = __builtin_amdgcn_rcpf(s + 1e-37f);
    return fmaxf(fmaf(n0 + n1, r, dv), 0.f);
}

// E1 + proj2 fused, grid-strided, launch_bounds(256,8).
// proj2 dot: W2 staged in LDS as b128 k-quads; per node: 16 ds_read_b128 +
// 16 b64 h-broadcasts + 64 fdot2.
__global__ void __launch_bounds__(256, 8) e1p2_kernel(
        const float* __restrict__ pos,
        const int* __restrict__ offsets, const int* __restrict__ sorted_src,
        const unsigned* __restrict__ g1,
        const float* __restrict__ W1_pos, const float* __restrict__ b1_pos,
        const float* __restrict__ W2_src, const float* __restrict__ W2_val,
        const float* __restrict__ W2_pos,
        unsigned* __restrict__ g2, int N) {
    __shared__ uint4 W4q[16 * 64];    // [q][c]: k-quad (s01,s23,v01,v23), 16KB
    __shared__ __half hsh[4][64];
    int tid = threadIdx.x, lane = tid & 63, wid = tid >> 6;
    for (int idx = tid; idx < 1024; idx += 256) {
        int q = idx >> 6, c = idx & 63, k = 4 * q;
        H2U s01, s23, v01, v23;
        s01.hh = __floats2half2_rn(W2_src[k * 64 + c], W2_src[(k + 1) * 64 + c]);
        s23.hh = __floats2half2_rn(W2_src[(k + 2) * 64 + c], W2_src[(k + 3) * 64 + c]);
        v01.hh = __floats2half2_rn(W2_val[k * 64 + c], W2_val[(k + 1) * 64 + c]);
        v23.hh = __floats2half2_rn(W2_val[(k + 2) * 64 + c], W2_val[(k + 3) * 64 + c]);
        W4q[idx] = make_uint4(s01.u, s23.u, v01.u, v23.u);
    }
    __syncthreads();

    float w1p0 = W1_pos[lane], w1p1 = W1_pos[64 + lane], w1p2 = W1_pos[128 + lane];
    float bp1 = b1_pos[lane];
    float w2p0 = W2_pos[lane], w2p1 = W2_pos[64 + lane], w2p2 = W2_pos[128 + lane];
    int laneoff = lane * 4;
    int nwav = gridDim.x * 4;

    for (int node = blockIdx.x * 4 + wid; node < N; node += nwav) {
        float p0 = pos[node * 3 + 0], p1 = pos[node * 3 + 1], p2 = pos[node * 3 + 2];
        float dpos = fmaf(p0, w1p0, fmaf(p1, w1p1, p2 * w1p2));
        float hval = edge_node(node, laneoff, offsets, sorted_src,
                               (const char*)g1, dpos + bp1);
        hsh[wid][lane] = __float2half(hval);   // same-wave publish (all lanes)
        const uint2* hq = (const uint2*)hsh[wid];
        float as = 0.f, vv = 0.f;
        #pragma unroll 4
        for (int q = 0; q < 16; ++q) {
            uint2 hu = hq[q];                  // b64 broadcast: h quad
            H2U h01, h23; h01.u = hu.x; h23.u = hu.y;
            uint4 wq = W4q[q * 64 + lane];     // ds_read_b128
            H2U a0, a1, b0, b1;
            a0.u = wq.x; a1.u = wq.y; b0.u = wq.z; b1.u = wq.w;
            as = fdot2(h01.hf, a0.hf, as);
            as = fdot2(h23.hf, a1.hf, as);
            vv = fdot2(h01.hf, b0.hf, vv);
            vv = fdot2(h23.hf, b1.hf, vv);
        }
        float cc = fmaf(p0, w2p0, fmaf(p1, w2p1, p2 * w2p2));
        g2[node * 64 + lane] = pack_payload(as + cc, vv - cc);
    }
}

// E2 + fused relu/fc1/relu/fc2 head, grid-strided. fc1 via fdot2 with Wfc1
// pairs held in 16 VGPRs (fits the 64-VGPR budget at 8 waves/EU).
__global__ void __launch_bounds__(256, 8) e2head_kernel(
        const float* __restrict__ pos,
        const int* __restrict__ offsets, const int* __restrict__ sorted_src,
        const unsigned* __restrict__ g2,
        const float* __restrict__ W2_pos, const float* __restrict__ b2_pos,
        const float* __restrict__ Wfc1, const float* __restrict__ bfc1,
        const float* __restrict__ Wfc2, const float* __restrict__ bfc2,
        float* __restrict__ out, int N) {
    __shared__ __half hsh[4][64];
    int tid = threadIdx.x, lane = tid & 63, wid = tid >> 6;
    int c = lane & 31, khb = (lane >> 5) * 16;
    unsigned Wr[16];                  // this lane's fc1 k-pairs (16 VGPRs)
    #pragma unroll
    for (int j = 0; j < 16; ++j) {
        H2U w;
        w.hh = __floats2half2_rn(Wfc1[(2 * (khb + j)) * 32 + c],
                                 Wfc1[(2 * (khb + j) + 1) * 32 + c]);
        Wr[j] = w.u;
    }

    float wp0 = W2_pos[lane], wp1 = W2_pos[64 + lane], wp2 = W2_pos[128 + lane];
    float bp = b2_pos[lane];
    float bfc1c = bfc1[c], wfc2c = Wfc2[c], bias2 = bfc2[0];
    int laneoff = lane * 4;
    int nwav = gridDim.x * 4;

    for (int node = blockIdx.x * 4 + wid; node < N; node += nwav) {
        float p0 = pos[node * 3 + 0], p1 = pos[node * 3 + 1], p2 = pos[node * 3 + 2];
        float dpos = fmaf(p0, wp0, fmaf(p1, wp1, p2 * wp2));
        float hval = edge_node(node, laneoff, offsets, sorted_src,
                               (const char*)g2, dpos + bp);
        hsh[wid][lane] = __float2half(hval);   // all-lane same-wave publish
        const hf2* h2 = (const hf2*)hsh[wid];
        float t2 = 0.f;
        #pragma unroll
        for (int j = 0; j < 16; ++j) {
            hf2 hk = h2[khb + j];              // 4B broadcast read
            H2U w; w.u = Wr[j];
            t2 = fdot2(hk, w.hf, t2);
        }
        t2 += __shfl_down(t2, 32);             // all lanes execute
        t2 = fmaxf(t2 + bfc1c, 0.f) * wfc2c;
        t2 = (lane < 32) ? t2 : 0.f;
        #pragma unroll
        for (int off = 16; off >= 1; off >>= 1) t2 += __shfl_down(t2, off);
        if (lane == 0) out[node] = t2 + bias2;
    }
}

extern "C" void kernel_launch(void* const* d_in, const int* in_sizes, int n_in,
                              void* d_out, int out_size, void* d_ws, size_t ws_size,
                              hipStream_t stream) {
    const float* x   = (const float*)d_in[0];
    const float* pos = (const float*)d_in[1];
    const int* eidx  = (const int*)d_in[2];
    const float* W1_src = (const float*)d_in[4];
    // d_in[5] = W1_dst: cancels in softmax
    const float* W1_val = (const float*)d_in[6];
    const float* W1_pos = (const float*)d_in[7];
    const float* b1_pos = (const float*)d_in[8];
    const float* W2_src = (const float*)d_in[9];
    // d_in[10] = W2_dst: cancels in softmax
    const float* W2_val = (const float*)d_in[11];
    const float* W2_pos = (const float*)d_in[12];
    const float* b2_pos = (const float*)d_in[13];
    const float* W_fc1  = (const float*)d_in[14];
    const float* b_fc1  = (const float*)d_in[15];
    const float* W_fc2  = (const float*)d_in[16];
    const float* b_fc2  = (const float*)d_in[17];

    const int N = in_sizes[0] / 3;
    const int E = in_sizes[2] / 2;
    const int* src = eidx;
    const int* dst = eidx + E;
    const int nsb = (N + 1023) / 1024;   // 49 for N=50K (must be <=64)

    char* w = (char*)d_ws;
    auto carve = [&](size_t bytes) -> void* {
        void* p = (void*)w;
        w += (bytes + 255) & ~size_t(255);
        return p;
    };
    int*      count8     = (int*)carve((size_t)8 * N * 4);
    int*      offsets    = (int*)carve((size_t)(N + 1) * 4);
    int*      base8      = (int*)carve((size_t)8 * N * 4);
    int*      chunksum   = (int*)carve((size_t)64 * 4);
    int*      rank       = (int*)carve((size_t)E * 4);
    int*      sorted_src = (int*)carve((size_t)E * 4);
    unsigned* g1         = (unsigned*)carve((size_t)N * 64 * 4);
    unsigned* g2         = (unsigned*)carve((size_t)N * 64 * 4);

    hipMemsetAsync(count8, 0, (size_t)8 * N * 4, stream);
    hist_proj1_kernel<<<2048, 256, 0, stream>>>(
        dst, count8, rank, x, pos, W1_src, W1_val, W1_pos, g1, N, E);
    scan_sum_kernel<<<nsb, 256, 0, stream>>>(count8, chunksum, N);
    scan_emit_kernel<<<nsb, 256, 0, stream>>>(count8, chunksum, offsets, base8,
                                              N, nsb);
    scatter_kernel<<<2048, 256, 0, stream>>>(src, dst, rank, base8,
                                             sorted_src, N, E);
    e1p2_kernel<<<2048, 256, 0, stream>>>(
        pos, offsets, sorted_src, g1, W1_pos, b1_pos, W2_src, W2_val, W2_pos, g2, N);
    e2head_kernel<<<2048, 256, 0, stream>>>(
        pos, offsets, sorted_src, g2, W2_pos, b2_pos,
        W_fc1, b_fc1, W_fc2, b_fc2, (float*)d_out, N);
}